// Round 4
// baseline (7823.473 us; speedup 1.0000x reference)
//
#include <hip/hip_runtime.h>
#include <stdint.h>

#define B_   128
#define T_   128
#define D_   2048
#define H_   512
#define G3   1536
#define CH   1024
#define KC   512
#define OUTD 2048
#define IND  5120
#define TP   168
#define MPAD 160

typedef short vb8 __attribute__((ext_vector_type(8)));
typedef float v4f __attribute__((ext_vector_type(4)));

__device__ __forceinline__ unsigned short f2b(float f) {
  unsigned u = __float_as_uint(f);
  u = (u + 0x7FFFu + ((u >> 16) & 1u)) >> 16;
  return (unsigned short)u;
}
__device__ __forceinline__ float b2f(unsigned short u) {
  return __uint_as_float((unsigned)u << 16);
}

__device__ __forceinline__ void gl16(const unsigned short* g, unsigned short* l) {
  __builtin_amdgcn_global_load_lds(
      (const __attribute__((address_space(1))) void*)g,
      (__attribute__((address_space(3))) void*)l, 16, 0, 0);
}

// ---------------- f32 -> bf16 elementwise ----------------
__global__ void k_cvt(const float* __restrict__ in, unsigned short* __restrict__ out, int n4) {
  int stride = gridDim.x * blockDim.x;
  for (int i = blockIdx.x * blockDim.x + threadIdx.x; i < n4; i += stride) {
    float4 v = reinterpret_cast<const float4*>(in)[i];
    ushort4 o;
    o.x = f2b(v.x); o.y = f2b(v.y); o.z = f2b(v.z); o.w = f2b(v.w);
    reinterpret_cast<ushort4*>(out)[i] = o;
  }
}

// ---------------- fc_w [5120][2048] f32 -> [2048][5120] bf16 ----------------
__global__ void k_tcvt(const float* __restrict__ in, unsigned short* __restrict__ out) {
  __shared__ float tile[32][33];
  const int tx = threadIdx.x & 31;
  const int ty = threadIdx.x >> 5; // 0..7
  const int n0 = blockIdx.x * 32;
  const int k0 = blockIdx.y * 32;
#pragma unroll
  for (int i = 0; i < 4; ++i)
    tile[ty + 8 * i][tx] = in[(size_t)(k0 + ty + 8 * i) * OUTD + n0 + tx];
  __syncthreads();
#pragma unroll
  for (int i = 0; i < 4; ++i)
    out[(size_t)(n0 + ty + 8 * i) * IND + k0 + tx] = f2b(tile[tx][ty + 8 * i]);
}

// ---------------- bf16 MFMA GEMM, global_load_lds staging (m97 recipe) ----------------
// C[m][n] = sum_k A[m][k] * Bm[n][k]  (+bias[n])
// EPI==0: store C (CB: 1=bf16, 0=f32). EPI==1: conv epilogue (relu+max over tau, atomicMax).
template<int EPI, int CB>
__global__ __launch_bounds__(256) void k_gemm(
    const unsigned short* __restrict__ A,
    const unsigned short* __restrict__ Bm,
    const float* __restrict__ bias,
    void* __restrict__ Cv,
    int K, int lda, int ldc, int convw)
{
  __shared__ unsigned short sA[128 * 32];
  __shared__ unsigned short sB[128 * 32];
  float*          C32 = (float*)Cv;
  unsigned short* C16 = (unsigned short*)Cv;

  const int tid  = threadIdx.x;
  const int lane = tid & 63;
  const int wv   = tid >> 6;
  const int wr   = wv >> 1;
  const int wc   = wv & 1;
  const int m0   = blockIdx.x * 128;
  const int n0   = blockIdx.y * 128;

  // staging addresses: wave wv stages chunks {2wv, 2wv+1}; chunk = 16 rows x 64B
  const unsigned short* ag[2];
  const unsigned short* bg[2];
  unsigned short* al[2];
  unsigned short* bl[2];
#pragma unroll
  for (int q = 0; q < 2; ++q) {
    int c  = wv * 2 + q;
    int r  = c * 16 + (lane >> 2);
    int kc = (lane & 3) * 8;
    long abase;
    if (EPI == 1) {
      int m   = m0 + r;
      int b   = m / MPAD;
      int tau = m - b * MPAD;
      abase = (long)(b * TP + 4 + tau - (convw - 1)) * CH;
    } else {
      abase = (long)(m0 + r) * lda;
    }
    ag[q] = A + abase + kc;
    bg[q] = Bm + (long)(n0 + r) * K + kc;
    al[q] = sA + c * 512;
    bl[q] = sB + c * 512;
  }

  v4f acc[4][4] = {};
  const int kq = (lane >> 4) * 8;
  const int fr = lane & 15;

  for (int k0 = 0; k0 < K; k0 += 32) {
    if (k0) __syncthreads();
#pragma unroll
    for (int q = 0; q < 2; ++q) {
      gl16(ag[q] + k0, al[q]);
      gl16(bg[q] + k0, bl[q]);
    }
    __syncthreads();
    vb8 af[4], bfr[4];
#pragma unroll
    for (int i = 0; i < 4; ++i) {
      af[i]  = *reinterpret_cast<const vb8*>(sA + (wr * 64 + i * 16 + fr) * 32 + kq);
      bfr[i] = *reinterpret_cast<const vb8*>(sB + (wc * 64 + i * 16 + fr) * 32 + kq);
    }
#pragma unroll
    for (int i = 0; i < 4; ++i)
#pragma unroll
      for (int j = 0; j < 4; ++j)
        acc[i][j] = __builtin_amdgcn_mfma_f32_16x16x32_bf16(af[i], bfr[j], acc[i][j], 0, 0, 0);
  }

  const int rl = lane >> 4;
#pragma unroll
  for (int i = 0; i < 4; ++i) {
#pragma unroll
    for (int j = 0; j < 4; ++j) {
      int col = n0 + wc * 64 + j * 16 + fr;
      float bs = bias[col];
      if (EPI == 0) {
#pragma unroll
        for (int r = 0; r < 4; ++r) {
          int m = m0 + wr * 64 + i * 16 + rl * 4 + r;
          float v = acc[i][j][r] + bs;
          if (CB) C16[(long)m * ldc + col] = f2b(v);
          else    C32[(long)m * ldc + col] = v;
        }
      } else {
        int mf = m0 + wr * 64 + i * 16;     // frag first row; 16 | 160 so single b per frag
        int b  = mf / MPAD;
        int tf = mf - b * MPAD;
        float mx = 0.f;
#pragma unroll
        for (int r = 0; r < 4; ++r) {
          int tau = tf + rl * 4 + r;
          float v = acc[i][j][r] + bs;
          v = v > 0.f ? v : 0.f;
          if (tau < T_ + convw - 1) mx = v > mx ? v : mx;
        }
        mx = fmaxf(mx, __shfl_xor(mx, 16));
        mx = fmaxf(mx, __shfl_xor(mx, 32));
        if (rl == 0 && tf < T_ + convw - 1)
          atomicMax(reinterpret_cast<int*>(C32 + (long)b * ldc + col), __float_as_int(mx));
      }
    }
  }
}

// ---------------- bidirectional GRU scan, batch-decomposed ----------------
// 16 WGs (8 per direction), each owns 16 batches and computes the FULL 512-unit h.
// h double-buffered in WG-local LDS (XOR-swizzled). No inter-WG communication:
// the step barrier is a plain __syncthreads(). W_hh (bf16) is streamed from L2
// every step (read-only, ~1.57MB/dir; one fwd + one bwd WG per XCD -> L2-resident).
__global__ __launch_bounds__(256, 1) void k_scan(
    const unsigned short* __restrict__ whh16,   // [2][1536][512] bf16 (fwd, bwd)
    const float* __restrict__ bhhf, const float* __restrict__ bhhb,
    const unsigned short* __restrict__ xw,      // [2][B][T][1536] bf16
    const int* __restrict__ lengths,
    unsigned short* __restrict__ xpad,
    float* __restrict__ meang)
{
  __shared__ unsigned short hls[2][16 * 512];   // 32 KB, XOR-swizzled rows
  const int wg   = blockIdx.x;                  // 0..15
  const int dir  = wg >> 3;
  const int b0   = (wg & 7) * 16;
  const int tid  = threadIdx.x;
  const int lane = tid & 63;
  const int wv   = tid >> 6;                    // 0..3: unit slice [wv*128, +128)
  const int fr   = lane & 15;
  const int rl   = lane >> 4;                   // 0..3
  const int kq   = rl * 8;

  const unsigned short* Wd  = whh16 + (size_t)dir * (3 * H_ * H_);
  const float*          bhh = dir ? bhhb : bhhf;
  const unsigned short* xwd = xw + (size_t)dir * ((size_t)B_ * T_ * G3);

  // 24 n-tiles per wave: rows g*512 + wv*128 + j*16 + fr
  long  woff[3][8];
  float bh[3][8];
#pragma unroll
  for (int g = 0; g < 3; ++g)
#pragma unroll
    for (int j = 0; j < 8; ++j) {
      int u = wv * 128 + j * 16 + fr;
      woff[g][j] = ((long)(g * H_ + u)) * H_ + kq;
      bh[g][j]   = bhh[g * H_ + u];
    }

  int    mylen[4];
  size_t xb[4];
#pragma unroll
  for (int r = 0; r < 4; ++r) {
    int b = b0 + rl * 4 + r;
    mylen[r] = lengths[b];
    xb[r] = (size_t)b * T_ * G3;
  }
  float hst[32], macc[32];
#pragma unroll
  for (int i = 0; i < 32; ++i) { hst[i] = 0.f; macc[i] = 0.f; }

  for (int s = 0; s < T_; ++s) {
    const int t = dir ? (T_ - 1 - s) : s;

    // prefetch this step's xw gates into registers; latency hides under MFMA
    unsigned short uxw[3][8][4];
#pragma unroll
    for (int g = 0; g < 3; ++g)
#pragma unroll
      for (int j = 0; j < 8; ++j)
#pragma unroll
        for (int r = 0; r < 4; ++r)
          uxw[g][j][r] = xwd[xb[r] + (size_t)t * G3 + g * H_ + wv * 128 + j * 16 + fr];

    v4f acc[3][8] = {};
    if (s > 0) {
      const char* hb = (const char*)hls[(s - 1) & 1];
#pragma unroll 4
      for (int ks = 0; ks < 16; ++ks) {
        vb8 a = *reinterpret_cast<const vb8*>(
            hb + ((fr * 1024 + ks * 64 + kq * 2) ^ ((fr & 7) << 4)));
#pragma unroll
        for (int g = 0; g < 3; ++g)
#pragma unroll
          for (int j = 0; j < 8; ++j) {
            vb8 bfr = *reinterpret_cast<const vb8*>(Wd + woff[g][j] + ks * 32);
            acc[g][j] = __builtin_amdgcn_mfma_f32_16x16x32_bf16(a, bfr, acc[g][j], 0, 0, 0);
          }
      }
    }

    char* hw = (char*)hls[s & 1];
#pragma unroll
    for (int j = 0; j < 8; ++j)
#pragma unroll
      for (int r = 0; r < 4; ++r) {
        const int idx = j * 4 + r;
        const int lb  = rl * 4 + r;
        const int u   = wv * 128 + j * 16 + fr;
        float xr = b2f(uxw[0][j][r]), xz = b2f(uxw[1][j][r]), xn = b2f(uxw[2][j][r]);
        float hr = acc[0][j][r] + bh[0][j];
        float hz = acc[1][j][r] + bh[1][j];
        float hn = acc[2][j][r] + bh[2][j];
        float rr = 1.f / (1.f + __expf(-(xr + hr)));
        float z  = 1.f / (1.f + __expf(-(xz + hz)));
        float ax = xn + rr * hn;
        float n  = 2.f / (1.f + __expf(-2.f * ax)) - 1.f;
        float h  = (1.f - z) * n + z * hst[idx];
        hst[idx] = h;
        *reinterpret_cast<unsigned short*>(
            hw + ((lb * 1024 + u * 2) ^ ((lb & 7) << 4))) = f2b(h);
        if (t < mylen[r]) {
          xpad[((size_t)(b0 + lb) * TP + 4 + t) * CH + dir * H_ + u] = f2b(h);
          macc[idx] += h;
        }
      }
    __syncthreads();
  }

#pragma unroll
  for (int j = 0; j < 8; ++j)
#pragma unroll
    for (int r = 0; r < 4; ++r)
      meang[(size_t)(b0 + rl * 4 + r) * CH + dir * H_ + wv * 128 + j * 16 + fr] =
          macc[j * 4 + r] / (float)mylen[r];
}

// ---------------- feats assembly [128][5120] bf16 ----------------
__global__ void k_feats(const float* __restrict__ mg, const float* __restrict__ co,
                        const float* __restrict__ vo, unsigned short* __restrict__ out) {
  int i = blockIdx.x * 256 + threadIdx.x;
  int b = i / IND, c = i - b * IND;
  float v;
  if (c < CH) v = mg[b * CH + c];
  else if (c < CH + OUTD) v = co[b * OUTD + (c - CH)];
  else v = vo[b * D_ + (c - CH - OUTD)];
  out[i] = f2b(v);
}

// ---------------- BN + L2 normalize ----------------
__global__ __launch_bounds__(256) void k_bnnorm(const float* __restrict__ x,
    const float* __restrict__ g, const float* __restrict__ bt,
    const float* __restrict__ mn, const float* __restrict__ vr,
    float* __restrict__ out) {
  const int b = blockIdx.x;
  __shared__ float red[4];
  float vals[8];
  float ss = 0.f;
#pragma unroll
  for (int i = 0; i < 8; ++i) {
    int c = threadIdx.x + i * 256;
    float y = g[c] * (x[(size_t)b * OUTD + c] - mn[c]) / sqrtf(vr[c] + 1e-5f) + bt[c];
    vals[i] = y;
    ss += y * y;
  }
#pragma unroll
  for (int s2 = 1; s2 < 64; s2 <<= 1) ss += __shfl_xor(ss, s2);
  if ((threadIdx.x & 63) == 0) red[threadIdx.x >> 6] = ss;
  __syncthreads();
  float inv = 1.f / sqrtf(red[0] + red[1] + red[2] + red[3]);
#pragma unroll
  for (int i = 0; i < 8; ++i)
    out[(size_t)b * OUTD + threadIdx.x + i * 256] = vals[i] * inv;
}

extern "C" void kernel_launch(void* const* d_in, const int* in_sizes, int n_in,
                              void* d_out, int out_size, void* d_ws, size_t ws_size,
                              hipStream_t stream) {
  (void)in_sizes; (void)n_in; (void)out_size; (void)ws_size;
  const float* videos = (const float*)d_in[0];
  const float* vorig  = (const float*)d_in[1];
  const int*   lens   = (const int*)d_in[2];
  const float* wihf = (const float*)d_in[4];
  const float* whhf = (const float*)d_in[5];
  const float* bihf = (const float*)d_in[6];
  const float* bhhf = (const float*)d_in[7];
  const float* wihb = (const float*)d_in[8];
  const float* whhb = (const float*)d_in[9];
  const float* bihb = (const float*)d_in[10];
  const float* bhhb = (const float*)d_in[11];
  const float* cw[4] = {(const float*)d_in[12], (const float*)d_in[14],
                        (const float*)d_in[16], (const float*)d_in[18]};
  const float* cb[4] = {(const float*)d_in[13], (const float*)d_in[15],
                        (const float*)d_in[17], (const float*)d_in[19]};
  const float* fcw = (const float*)d_in[20];
  const float* fcb = (const float*)d_in[21];
  const float* bng = (const float*)d_in[22];
  const float* bnb = (const float*)d_in[23];
  const float* bnm = (const float*)d_in[24];
  const float* bnv = (const float*)d_in[25];
  float* out = (float*)d_out;

  char* ws = (char*)d_ws;
  size_t off = 0;
  auto alloc = [&](size_t bytes) -> void* {
    void* p = ws + off;
    off = (off + bytes + 255) & ~(size_t)255;
    return p;
  };
  unsigned short* xw16   = (unsigned short*)alloc((size_t)2 * B_ * T_ * G3 * 2);  // 100.7 MB
  unsigned short* whh16  = (unsigned short*)alloc((size_t)2 * 3 * H_ * H_ * 2);   // 3.1 MB
  float*          meang  = (float*)alloc((size_t)B_ * CH * 4);
  float*          conout = (float*)alloc((size_t)B_ * OUTD * 4);
  unsigned short* feats  = (unsigned short*)alloc((size_t)B_ * IND * 2);
  float*          fcout  = (float*)alloc((size_t)B_ * OUTD * 4);
  unsigned short* wihf16 = (unsigned short*)alloc((size_t)G3 * D_ * 2);
  unsigned short* wihb16 = (unsigned short*)alloc((size_t)G3 * D_ * 2);
  unsigned short* cw16   = (unsigned short*)alloc((size_t)KC * 14 * CH * 2);
  unsigned short* vid16  = (unsigned short*)alloc((size_t)B_ * T_ * D_ * 2);      // 67.1 MB
  // vid16 is dead after the xw GEMMs; xpad (44.0 MB) + fcT (21.0 MB) alias it.
  unsigned short* xpad = vid16;
  unsigned short* fcT  = vid16 + (size_t)B_ * TP * CH;
  // total ws usage ~200 MB

  hipMemsetAsync(conout, 0, (size_t)B_ * OUTD * 4, stream);

  // pre-convert all GEMM operands to bf16
  k_cvt<<<2048, 256, 0, stream>>>(videos, vid16, B_ * T_ * D_ / 4);
  k_cvt<<<512, 256, 0, stream>>>(wihf, wihf16, G3 * D_ / 4);
  k_cvt<<<512, 256, 0, stream>>>(wihb, wihb16, G3 * D_ / 4);
  k_cvt<<<768, 256, 0, stream>>>(whhf, whh16, 3 * H_ * H_ / 4);
  k_cvt<<<768, 256, 0, stream>>>(whhb, whh16 + (size_t)3 * H_ * H_, 3 * H_ * H_ / 4);
  {
    size_t cwoff = 0;
    for (int i = 0; i < 4; ++i) {
      int w = i + 2;
      int n = KC * w * CH;
      k_cvt<<<256, 256, 0, stream>>>(cw[i], cw16 + cwoff, n / 4);
      cwoff += (size_t)n;
    }
  }

  // xw = videos @ w_ih^T + b_ih (both directions), bf16 out
  k_gemm<0, 1><<<dim3(128, 12), 256, 0, stream>>>(vid16, wihf16, bihf, xw16, D_, D_, G3, 0);
  k_gemm<0, 1><<<dim3(128, 12), 256, 0, stream>>>(vid16, wihb16, bihb,
                                                  xw16 + (size_t)B_ * T_ * G3, D_, D_, G3, 0);

  // vid16 now dead: init aliased xpad + fcT
  hipMemsetAsync(xpad, 0, (size_t)B_ * TP * CH * 2, stream);
  k_tcvt<<<dim3(64, 160), 256, 0, stream>>>(fcw, fcT);

  // recurrent scan: 16 independent WGs, no inter-WG sync
  k_scan<<<dim3(16), dim3(256), 0, stream>>>(whh16, bhhf, bhhb, xw16, lens, xpad, meang);

  // convs (as GEMM over padded time) with fused relu+bias+time-max
  {
    size_t cwoff = 0;
    for (int i = 0; i < 4; ++i) {
      int w = i + 2;
      k_gemm<1, 0><<<dim3(160, 4), 256, 0, stream>>>(xpad, cw16 + cwoff, cb[i],
                                                     conout + i * KC, w * CH, 0, OUTD, w);
      cwoff += (size_t)KC * w * CH;
    }
  }

  k_feats<<<2560, 256, 0, stream>>>(meang, conout, vorig, feats);
  k_gemm<0, 0><<<dim3(1, 16), 256, 0, stream>>>(feats, fcT, fcb, fcout, IND, IND, OUTD, 0);
  k_bnnorm<<<B_, 256, 0, stream>>>(fcout, bng, bnb, bnm, bnv, out);
}

// Round 5
// 1939.606 us; speedup vs baseline: 4.0335x; 4.0335x over previous
//
#include <hip/hip_runtime.h>
#include <stdint.h>

#define B_   128
#define T_   128
#define D_   2048
#define H_   512
#define G3   1536
#define CH   1024
#define KC   512
#define OUTD 2048
#define IND  5120
#define TP   168
#define MPAD 160

typedef short vb8 __attribute__((ext_vector_type(8)));
typedef float v4f __attribute__((ext_vector_type(4)));

__device__ __forceinline__ unsigned short f2b(float f) {
  unsigned u = __float_as_uint(f);
  u = (u + 0x7FFFu + ((u >> 16) & 1u)) >> 16;
  return (unsigned short)u;
}
__device__ __forceinline__ float b2f(unsigned short u) {
  return __uint_as_float((unsigned)u << 16);
}

__device__ __forceinline__ void gl16(const unsigned short* g, unsigned short* l) {
  __builtin_amdgcn_global_load_lds(
      (const __attribute__((address_space(1))) void*)g,
      (__attribute__((address_space(3))) void*)l, 16, 0, 0);
}

// ---------------- f32 -> bf16 elementwise ----------------
__global__ void k_cvt(const float* __restrict__ in, unsigned short* __restrict__ out, int n4) {
  int stride = gridDim.x * blockDim.x;
  for (int i = blockIdx.x * blockDim.x + threadIdx.x; i < n4; i += stride) {
    float4 v = reinterpret_cast<const float4*>(in)[i];
    ushort4 o;
    o.x = f2b(v.x); o.y = f2b(v.y); o.z = f2b(v.z); o.w = f2b(v.w);
    reinterpret_cast<ushort4*>(out)[i] = o;
  }
}

// ---------------- fc_w [5120][2048] f32 -> [2048][5120] bf16 ----------------
__global__ void k_tcvt(const float* __restrict__ in, unsigned short* __restrict__ out) {
  __shared__ float tile[32][33];
  const int tx = threadIdx.x & 31;
  const int ty = threadIdx.x >> 5; // 0..7
  const int n0 = blockIdx.x * 32;
  const int k0 = blockIdx.y * 32;
#pragma unroll
  for (int i = 0; i < 4; ++i)
    tile[ty + 8 * i][tx] = in[(size_t)(k0 + ty + 8 * i) * OUTD + n0 + tx];
  __syncthreads();
#pragma unroll
  for (int i = 0; i < 4; ++i)
    out[(size_t)(n0 + ty + 8 * i) * IND + k0 + tx] = f2b(tile[tx][ty + 8 * i]);
}

// ---------------- bf16 MFMA GEMM, global_load_lds staging (m97 recipe) ----------------
// C[m][n] = sum_k A[m][k] * Bm[n][k]  (+bias[n])
// EPI==0: store C (CB: 1=bf16, 0=f32). EPI==1: conv epilogue (relu+max over tau, atomicMax).
template<int EPI, int CB>
__global__ __launch_bounds__(256) void k_gemm(
    const unsigned short* __restrict__ A,
    const unsigned short* __restrict__ Bm,
    const float* __restrict__ bias,
    void* __restrict__ Cv,
    int K, int lda, int ldc, int convw)
{
  __shared__ unsigned short sA[128 * 32];
  __shared__ unsigned short sB[128 * 32];
  float*          C32 = (float*)Cv;
  unsigned short* C16 = (unsigned short*)Cv;

  const int tid  = threadIdx.x;
  const int lane = tid & 63;
  const int wv   = tid >> 6;
  const int wr   = wv >> 1;
  const int wc   = wv & 1;
  const int m0   = blockIdx.x * 128;
  const int n0   = blockIdx.y * 128;

  // staging addresses: wave wv stages chunks {2wv, 2wv+1}; chunk = 16 rows x 64B
  const unsigned short* ag[2];
  const unsigned short* bg[2];
  unsigned short* al[2];
  unsigned short* bl[2];
#pragma unroll
  for (int q = 0; q < 2; ++q) {
    int c  = wv * 2 + q;
    int r  = c * 16 + (lane >> 2);
    int kc = (lane & 3) * 8;
    long abase;
    if (EPI == 1) {
      int m   = m0 + r;
      int b   = m / MPAD;
      int tau = m - b * MPAD;
      abase = (long)(b * TP + 4 + tau - (convw - 1)) * CH;
    } else {
      abase = (long)(m0 + r) * lda;
    }
    ag[q] = A + abase + kc;
    bg[q] = Bm + (long)(n0 + r) * K + kc;
    al[q] = sA + c * 512;
    bl[q] = sB + c * 512;
  }

  v4f acc[4][4] = {};
  const int kq = (lane >> 4) * 8;
  const int fr = lane & 15;

  for (int k0 = 0; k0 < K; k0 += 32) {
    if (k0) __syncthreads();
#pragma unroll
    for (int q = 0; q < 2; ++q) {
      gl16(ag[q] + k0, al[q]);
      gl16(bg[q] + k0, bl[q]);
    }
    __syncthreads();
    vb8 af[4], bfr[4];
#pragma unroll
    for (int i = 0; i < 4; ++i) {
      af[i]  = *reinterpret_cast<const vb8*>(sA + (wr * 64 + i * 16 + fr) * 32 + kq);
      bfr[i] = *reinterpret_cast<const vb8*>(sB + (wc * 64 + i * 16 + fr) * 32 + kq);
    }
#pragma unroll
    for (int i = 0; i < 4; ++i)
#pragma unroll
      for (int j = 0; j < 4; ++j)
        acc[i][j] = __builtin_amdgcn_mfma_f32_16x16x32_bf16(af[i], bfr[j], acc[i][j], 0, 0, 0);
  }

  const int rl = lane >> 4;
#pragma unroll
  for (int i = 0; i < 4; ++i) {
#pragma unroll
    for (int j = 0; j < 4; ++j) {
      int col = n0 + wc * 64 + j * 16 + fr;
      float bs = bias[col];
      if (EPI == 0) {
#pragma unroll
        for (int r = 0; r < 4; ++r) {
          int m = m0 + wr * 64 + i * 16 + rl * 4 + r;
          float v = acc[i][j][r] + bs;
          if (CB) C16[(long)m * ldc + col] = f2b(v);
          else    C32[(long)m * ldc + col] = v;
        }
      } else {
        int mf = m0 + wr * 64 + i * 16;     // frag first row; 16 | 160 so single b per frag
        int b  = mf / MPAD;
        int tf = mf - b * MPAD;
        float mx = 0.f;
#pragma unroll
        for (int r = 0; r < 4; ++r) {
          int tau = tf + rl * 4 + r;
          float v = acc[i][j][r] + bs;
          v = v > 0.f ? v : 0.f;
          if (tau < T_ + convw - 1) mx = v > mx ? v : mx;
        }
        mx = fmaxf(mx, __shfl_xor(mx, 16));
        mx = fmaxf(mx, __shfl_xor(mx, 32));
        if (rl == 0 && tf < T_ + convw - 1)
          atomicMax(reinterpret_cast<int*>(C32 + (long)b * ldc + col), __float_as_int(mx));
      }
    }
  }
}

// ---------------- persistent bidirectional GRU scan, unit-split v2 ----------------
// 32 WGs x 512 thr (16 per direction), each owns 32 hidden units for ALL 128 batches.
// W_hh slice (96 rows x 512) in LDS, XOR-swizzled, loaded once. Wave wv owns the
// 16-batch M-tile [wv*16, wv*16+16) x all 6 N-tiles -> 96 MFMA/wave/step.
// h exchanged via global double-buffered bf16; per-direction counter barrier:
// release-add, RELAXED polls, one acquire fence. xw prefetched pre-barrier.
__global__ __launch_bounds__(512) void k_scan(
    const unsigned short* __restrict__ whh16,   // [2][1536][512] bf16
    const float* __restrict__ bhhf, const float* __restrict__ bhhb,
    const unsigned short* __restrict__ xw,      // [2][B][T][1536] bf16
    const int* __restrict__ lengths,
    unsigned short* __restrict__ hbuf,          // [2][2][128][512] bf16
    unsigned short* __restrict__ xpad,
    float* __restrict__ meang,
    unsigned int* __restrict__ cnt)
{
  __shared__ unsigned short sw[96 * 512];       // 96 KB, XOR-swizzled rows
  const int wg   = blockIdx.x;                  // 0..31
  const int dir  = wg >> 4;
  const int u0   = (wg & 15) * 32;
  const int tid  = threadIdx.x;                 // 0..511
  const int lane = tid & 63;
  const int wv   = tid >> 6;                    // 0..7 = M-tile
  const int fr   = lane & 15;
  const int rl   = lane >> 4;
  const int kq   = rl * 8;

  const unsigned short* Wd  = whh16 + (size_t)dir * (3 * H_ * H_);
  const float*          bhh = dir ? bhhb : bhhf;
  const unsigned short* xwd = xw + (size_t)dir * ((size_t)B_ * T_ * G3);
  unsigned short* hb = hbuf + dir * (2 * B_ * H_);
  unsigned int* mycnt = cnt + dir * 64;         // 256 B apart per direction

  // stage W slice: LDS row q = g*32+du  <->  W row g*512 + u0 + du ; swizzle ^((q&7)<<4)
  for (int i = tid; i < 96 * 64; i += 512) {
    int row  = i >> 6;
    int slot = i & 63;
    const unsigned short* src = Wd + (size_t)((row >> 5) * H_ + u0 + (row & 31)) * H_ + slot * 8;
    *reinterpret_cast<vb8*>((char*)sw + ((row * 1024 + slot * 16) ^ ((row & 7) << 4))) =
        *reinterpret_cast<const vb8*>(src);
  }
  __syncthreads();

  int mylen[4];
#pragma unroll
  for (int r = 0; r < 4; ++r) mylen[r] = lengths[wv * 16 + rl * 4 + r];

  float bh[3][2];
#pragma unroll
  for (int g = 0; g < 3; ++g)
#pragma unroll
    for (int j = 0; j < 2; ++j) bh[g][j] = bhh[g * H_ + u0 + j * 16 + fr];

  float hst[8], macc[8];
#pragma unroll
  for (int i = 0; i < 8; ++i) { hst[i] = 0.f; macc[i] = 0.f; }

  // prefetch step-0 xw gates
  unsigned short uxw[3][2][4];
  {
    const int t0 = dir ? (T_ - 1) : 0;
#pragma unroll
    for (int g = 0; g < 3; ++g)
#pragma unroll
      for (int j = 0; j < 2; ++j)
#pragma unroll
        for (int r = 0; r < 4; ++r)
          uxw[g][j][r] = xwd[((size_t)(wv * 16 + rl * 4 + r) * T_ + t0) * G3 +
                             g * H_ + u0 + j * 16 + fr];
  }

  for (int s = 0; s < T_; ++s) {
    const int t = dir ? (T_ - 1 - s) : s;

    v4f acc[3][2] = {};
    if (s > 0) {
      const unsigned short* arow = hb + ((s - 1) & 1) * (B_ * H_) + (wv * 16 + fr) * H_;
#pragma unroll 4
      for (int ks = 0; ks < 16; ++ks) {
        vb8 a = *reinterpret_cast<const vb8*>(arow + ks * 32 + kq);
#pragma unroll
        for (int g = 0; g < 3; ++g)
#pragma unroll
          for (int j = 0; j < 2; ++j) {
            vb8 wf = *reinterpret_cast<const vb8*>(
                (const char*)sw +
                (((g * 32 + j * 16 + fr) * 1024 + ks * 64 + rl * 16) ^ ((fr & 7) << 4)));
            acc[g][j] = __builtin_amdgcn_mfma_f32_16x16x32_bf16(a, wf, acc[g][j], 0, 0, 0);
          }
      }
    }

    unsigned short* hc = hb + (s & 1) * (B_ * H_);
#pragma unroll
    for (int j = 0; j < 2; ++j)
#pragma unroll
      for (int r = 0; r < 4; ++r) {
        const int idx = j * 4 + r;
        const int b   = wv * 16 + rl * 4 + r;
        const int u   = u0 + j * 16 + fr;
        float xr = b2f(uxw[0][j][r]), xz = b2f(uxw[1][j][r]), xn = b2f(uxw[2][j][r]);
        float hr = acc[0][j][r] + bh[0][j];
        float hz = acc[1][j][r] + bh[1][j];
        float hn = acc[2][j][r] + bh[2][j];
        float rr = 1.f / (1.f + __expf(-(xr + hr)));
        float z  = 1.f / (1.f + __expf(-(xz + hz)));
        float ax = xn + rr * hn;
        float n  = 2.f / (1.f + __expf(-2.f * ax)) - 1.f;
        float h  = (1.f - z) * n + z * hst[idx];
        hst[idx] = h;
        hc[b * H_ + u] = f2b(h);
        if (t < mylen[r]) {
          xpad[((size_t)b * TP + 4 + t) * CH + dir * H_ + u] = f2b(h);
          macc[idx] += h;
        }
      }

    if (s < T_ - 1) {
      // prefetch next step's xw (registers survive the fence)
      const int tn = dir ? (T_ - 2 - s) : (s + 1);
#pragma unroll
      for (int g = 0; g < 3; ++g)
#pragma unroll
        for (int j = 0; j < 2; ++j)
#pragma unroll
          for (int r = 0; r < 4; ++r)
            uxw[g][j][r] = xwd[((size_t)(wv * 16 + rl * 4 + r) * T_ + tn) * G3 +
                               g * H_ + u0 + j * 16 + fr];
      __syncthreads();                 // all waves' h-stores drained to L2
      if (tid == 0) {
        __hip_atomic_fetch_add(mycnt, 1u, __ATOMIC_RELEASE, __HIP_MEMORY_SCOPE_AGENT);
        const unsigned tgt = (unsigned)(s + 1) * 16;
        while (__hip_atomic_load(mycnt, __ATOMIC_RELAXED, __HIP_MEMORY_SCOPE_AGENT) < tgt)
          __builtin_amdgcn_s_sleep(1);
        __builtin_amdgcn_fence(__ATOMIC_ACQUIRE, "agent");  // one L1/L2 invalidate
      }
      __syncthreads();
    }
  }

#pragma unroll
  for (int j = 0; j < 2; ++j)
#pragma unroll
    for (int r = 0; r < 4; ++r)
      meang[(size_t)(wv * 16 + rl * 4 + r) * CH + dir * H_ + u0 + j * 16 + fr] =
          macc[j * 4 + r] / (float)mylen[r];
}

// ---------------- feats assembly [128][5120] bf16 ----------------
__global__ void k_feats(const float* __restrict__ mg, const float* __restrict__ co,
                        const float* __restrict__ vo, unsigned short* __restrict__ out) {
  int i = blockIdx.x * 256 + threadIdx.x;
  int b = i / IND, c = i - b * IND;
  float v;
  if (c < CH) v = mg[b * CH + c];
  else if (c < CH + OUTD) v = co[b * OUTD + (c - CH)];
  else v = vo[b * D_ + (c - CH - OUTD)];
  out[i] = f2b(v);
}

// ---------------- BN + L2 normalize ----------------
__global__ __launch_bounds__(256) void k_bnnorm(const float* __restrict__ x,
    const float* __restrict__ g, const float* __restrict__ bt,
    const float* __restrict__ mn, const float* __restrict__ vr,
    float* __restrict__ out) {
  const int b = blockIdx.x;
  __shared__ float red[4];
  float vals[8];
  float ss = 0.f;
#pragma unroll
  for (int i = 0; i < 8; ++i) {
    int c = threadIdx.x + i * 256;
    float y = g[c] * (x[(size_t)b * OUTD + c] - mn[c]) / sqrtf(vr[c] + 1e-5f) + bt[c];
    vals[i] = y;
    ss += y * y;
  }
#pragma unroll
  for (int s2 = 1; s2 < 64; s2 <<= 1) ss += __shfl_xor(ss, s2);
  if ((threadIdx.x & 63) == 0) red[threadIdx.x >> 6] = ss;
  __syncthreads();
  float inv = 1.f / sqrtf(red[0] + red[1] + red[2] + red[3]);
#pragma unroll
  for (int i = 0; i < 8; ++i)
    out[(size_t)b * OUTD + threadIdx.x + i * 256] = vals[i] * inv;
}

extern "C" void kernel_launch(void* const* d_in, const int* in_sizes, int n_in,
                              void* d_out, int out_size, void* d_ws, size_t ws_size,
                              hipStream_t stream) {
  (void)in_sizes; (void)n_in; (void)out_size; (void)ws_size;
  const float* videos = (const float*)d_in[0];
  const float* vorig  = (const float*)d_in[1];
  const int*   lens   = (const int*)d_in[2];
  const float* wihf = (const float*)d_in[4];
  const float* whhf = (const float*)d_in[5];
  const float* bihf = (const float*)d_in[6];
  const float* bhhf = (const float*)d_in[7];
  const float* wihb = (const float*)d_in[8];
  const float* whhb = (const float*)d_in[9];
  const float* bihb = (const float*)d_in[10];
  const float* bhhb = (const float*)d_in[11];
  const float* cw[4] = {(const float*)d_in[12], (const float*)d_in[14],
                        (const float*)d_in[16], (const float*)d_in[18]};
  const float* cb[4] = {(const float*)d_in[13], (const float*)d_in[15],
                        (const float*)d_in[17], (const float*)d_in[19]};
  const float* fcw = (const float*)d_in[20];
  const float* fcb = (const float*)d_in[21];
  const float* bng = (const float*)d_in[22];
  const float* bnb = (const float*)d_in[23];
  const float* bnm = (const float*)d_in[24];
  const float* bnv = (const float*)d_in[25];
  float* out = (float*)d_out;

  char* ws = (char*)d_ws;
  size_t off = 0;
  auto alloc = [&](size_t bytes) -> void* {
    void* p = ws + off;
    off = (off + bytes + 255) & ~(size_t)255;
    return p;
  };
  unsigned int*   cnt    = (unsigned int*)alloc(1024);
  unsigned short* xw16   = (unsigned short*)alloc((size_t)2 * B_ * T_ * G3 * 2);  // 100.7 MB
  unsigned short* whh16  = (unsigned short*)alloc((size_t)2 * 3 * H_ * H_ * 2);   // 3.1 MB
  unsigned short* hbuf   = (unsigned short*)alloc((size_t)2 * 2 * B_ * H_ * 2);   // 0.5 MB
  float*          meang  = (float*)alloc((size_t)B_ * CH * 4);
  float*          conout = (float*)alloc((size_t)B_ * OUTD * 4);
  unsigned short* feats  = (unsigned short*)alloc((size_t)B_ * IND * 2);
  float*          fcout  = (float*)alloc((size_t)B_ * OUTD * 4);
  unsigned short* wihf16 = (unsigned short*)alloc((size_t)G3 * D_ * 2);
  unsigned short* wihb16 = (unsigned short*)alloc((size_t)G3 * D_ * 2);
  unsigned short* cw16   = (unsigned short*)alloc((size_t)KC * 14 * CH * 2);
  unsigned short* vid16  = (unsigned short*)alloc((size_t)B_ * T_ * D_ * 2);      // 67.1 MB
  // vid16 is dead after the xw GEMMs; xpad (44.0 MB) + fcT (21.0 MB) alias it.
  unsigned short* xpad = vid16;
  unsigned short* fcT  = vid16 + (size_t)B_ * TP * CH;
  // total ws usage ~200 MB

  hipMemsetAsync(cnt, 0, 1024, stream);
  hipMemsetAsync(conout, 0, (size_t)B_ * OUTD * 4, stream);

  // pre-convert all GEMM operands to bf16
  k_cvt<<<2048, 256, 0, stream>>>(videos, vid16, B_ * T_ * D_ / 4);
  k_cvt<<<512, 256, 0, stream>>>(wihf, wihf16, G3 * D_ / 4);
  k_cvt<<<512, 256, 0, stream>>>(wihb, wihb16, G3 * D_ / 4);
  k_cvt<<<768, 256, 0, stream>>>(whhf, whh16, 3 * H_ * H_ / 4);
  k_cvt<<<768, 256, 0, stream>>>(whhb, whh16 + (size_t)3 * H_ * H_, 3 * H_ * H_ / 4);
  {
    size_t cwoff = 0;
    for (int i = 0; i < 4; ++i) {
      int w = i + 2;
      int n = KC * w * CH;
      k_cvt<<<256, 256, 0, stream>>>(cw[i], cw16 + cwoff, n / 4);
      cwoff += (size_t)n;
    }
  }

  // xw = videos @ w_ih^T + b_ih (both directions), bf16 out
  k_gemm<0, 1><<<dim3(128, 12), 256, 0, stream>>>(vid16, wihf16, bihf, xw16, D_, D_, G3, 0);
  k_gemm<0, 1><<<dim3(128, 12), 256, 0, stream>>>(vid16, wihb16, bihb,
                                                  xw16 + (size_t)B_ * T_ * G3, D_, D_, G3, 0);

  // vid16 now dead: init aliased xpad + fcT
  hipMemsetAsync(xpad, 0, (size_t)B_ * TP * CH * 2, stream);
  k_tcvt<<<dim3(64, 160), 256, 0, stream>>>(fcw, fcT);

  // recurrent scan: 32 WGs x 512 threads, unit-split, W in LDS
  k_scan<<<dim3(32), dim3(512), 0, stream>>>(whh16, bhhf, bhhb, xw16, lens,
                                             hbuf, xpad, meang, cnt);

  // convs (as GEMM over padded time) with fused relu+bias+time-max
  {
    size_t cwoff = 0;
    for (int i = 0; i < 4; ++i) {
      int w = i + 2;
      k_gemm<1, 0><<<dim3(160, 4), 256, 0, stream>>>(xpad, cw16 + cwoff, cb[i],
                                                     conout + i * KC, w * CH, 0, OUTD, w);
      cwoff += (size_t)KC * w * CH;
    }
  }

  k_feats<<<2560, 256, 0, stream>>>(meang, conout, vorig, feats);
  k_gemm<0, 0><<<dim3(1, 16), 256, 0, stream>>>(feats, fcT, fcb, fcout, IND, IND, OUTD, 0);
  k_bnnorm<<<B_, 256, 0, stream>>>(fcout, bng, bnb, bnm, bnv, out);
}